// Round 8
// baseline (287.121 us; speedup 1.0000x reference)
//
#include <hip/hip_runtime.h>
#include <cmath>

// GPTNeoXRoutedMLP: N=2048 tokens, H=1024, F=4096, E=8, topk=2.
// R8: 3-deep counted-vmcnt GEMM pipelines (no vmcnt(0) drain in main loop),
// BK=32, gemm1 48KB LDS (3 blk/CU), gemm2 36KB (4 blk/CU). B consumed via
// ds_read_b64_tr_b16 from subtiled LDS (verified R6/R7); A via gload_lds with
// XOR-swizzled pre-swizzled source. Router has no global atomics (R7).

#define H_DIM 1024
#define F_DIM 4096
#define E_NUM 8
#define N_TOK 2048
#define BK 32
#define MAX_SLOTS 5120
#define MAX_MT (MAX_SLOTS / 128)   // 40 row tiles
#define G1_GRID (MAX_MT * 32)      // 1280 (BN=128)
#define G2_GRID (MAX_MT * 16)      // 640  (BN=64)
#define CVT_BLKS 2048
#define WCHUNKS (E_NUM * H_DIM * F_DIM / 8)   // 4194304
#define XCHUNKS (N_TOK * H_DIM / 8)           // 262144

typedef short s16x4 __attribute__((ext_vector_type(4)));
typedef short s16x8 __attribute__((ext_vector_type(8)));
typedef float f32x4 __attribute__((ext_vector_type(4)));
typedef __attribute__((address_space(3))) const unsigned short* lds_us;

__device__ __forceinline__ unsigned short f2bf(float f) {
  unsigned int u = __float_as_uint(f);
  u += 0x7fffu + ((u >> 16) & 1u);   // RNE
  return (unsigned short)(u >> 16);
}

__device__ __forceinline__ void gload_lds16(const void* g, void* l) {
  __builtin_amdgcn_global_load_lds(
      (const __attribute__((address_space(1))) unsigned int*)g,
      (__attribute__((address_space(3))) unsigned int*)l, 16, 0, 0);
}

__device__ __forceinline__ int xcd_swz(int orig, int nwg) {
  const int cpx = nwg >> 3;   // nwg multiple of 8 (1280 / 640)
  return (orig & 7) * cpx + (orig >> 3);
}

__device__ __forceinline__ float fast_gelu(float v) {
  const float w = v * (1.0f + 0.044715f * v * v);
  const float t = __expf(-1.5957691216f * w);
  return v / (1.0f + t);
}

// hardware transpose read: lane l elem j <- lds[base + (l&15) + j*16 + (l>>4)*64]
template<int OFS>
__device__ __forceinline__ s16x4 trread(lds_us p) {
  s16x4 r;
  asm volatile("ds_read_b64_tr_b16 %0, %1 offset:%2" : "=v"(r) : "v"(p), "i"(OFS));
  return r;
}

// 4 col-group B-frags (gemm1), K=32 (one region per frag, halves at +0/+512B)
__device__ __forceinline__ void ld_b4(lds_us bp, s16x8 bb[4]) {
  s16x4 p0 = trread<0>(bp),    q0 = trread<512>(bp);
  s16x4 p1 = trread<1024>(bp), q1 = trread<1536>(bp);
  s16x4 p2 = trread<2048>(bp), q2 = trread<2560>(bp);
  s16x4 p3 = trread<3072>(bp), q3 = trread<3584>(bp);
  bb[0] = __builtin_shufflevector(p0, q0, 0, 1, 2, 3, 4, 5, 6, 7);
  bb[1] = __builtin_shufflevector(p1, q1, 0, 1, 2, 3, 4, 5, 6, 7);
  bb[2] = __builtin_shufflevector(p2, q2, 0, 1, 2, 3, 4, 5, 6, 7);
  bb[3] = __builtin_shufflevector(p3, q3, 0, 1, 2, 3, 4, 5, 6, 7);
}

__device__ __forceinline__ void ld_b2(lds_us bp, s16x8 bb[2]) {
  s16x4 p0 = trread<0>(bp),    q0 = trread<512>(bp);
  s16x4 p1 = trread<1024>(bp), q1 = trread<1536>(bp);
  bb[0] = __builtin_shufflevector(p0, q0, 0, 1, 2, 3, 4, 5, 6, 7);
  bb[1] = __builtin_shufflevector(p1, q1, 0, 1, 2, 3, 4, 5, 6, 7);
}

// grid-stride streaming f32 -> bf16
__device__ __forceinline__ void cvt_stream(const float* __restrict__ in,
                                           unsigned short* __restrict__ out,
                                           int blk, int nblk, int nchunks) {
  const int step = nblk * 256;
#pragma unroll 4
  for (int c = blk * 256 + threadIdx.x; c < nchunks; c += step) {
    const size_t i = (size_t)c * 8;
    f32x4 a = *(const f32x4*)(in + i);
    f32x4 b = *(const f32x4*)(in + i + 4);
    s16x8 u;
#pragma unroll
    for (int j = 0; j < 4; ++j) { u[j] = (short)f2bf(a[j]); u[4 + j] = (short)f2bf(b[j]); }
    *(s16x8*)&out[i] = u;
  }
}

// ---------------- prep: w1 cvt (2048) | x cvt (128) | router (512, no atomics) ----------------
__global__ __launch_bounds__(256) void prep_k(
    const float* __restrict__ w1, unsigned short* __restrict__ wbf1,
    const float* __restrict__ x, unsigned short* __restrict__ xb,
    const float* __restrict__ rw, int* __restrict__ topk_e, float* __restrict__ topk_s) {
  const int b = blockIdx.x;
  const int t = threadIdx.x;
  if (b < CVT_BLKS) { cvt_stream(w1, wbf1, b, CVT_BLKS, WCHUNKS); return; }
  if (b < CVT_BLKS + 128) { cvt_stream(x, xb, b - CVT_BLKS, 128, XCHUNKS); return; }
  const int n = (b - CVT_BLKS - 128) * 4 + (t >> 6);
  const int l = t & 63;
  float part[E_NUM];
#pragma unroll
  for (int e = 0; e < E_NUM; ++e) part[e] = 0.f;
  const float* xr = x + (size_t)n * H_DIM;
  for (int h = l; h < H_DIM; h += 64) {
    const float xv = xr[h];
    const float* rwr = rw + h * E_NUM;
#pragma unroll
    for (int e = 0; e < E_NUM; ++e) part[e] += xv * rwr[e];
  }
#pragma unroll
  for (int e = 0; e < E_NUM; ++e) {
#pragma unroll
    for (int off = 32; off > 0; off >>= 1) part[e] += __shfl_down(part[e], off);
  }
  if (l == 0) {
    float v0 = -3.4e38f, v1 = -3.4e38f;
    int i0 = 0, i1 = 0;
#pragma unroll
    for (int e = 0; e < E_NUM; ++e) {
      float v = part[e];
      if (v > v0) { v1 = v0; i1 = i0; v0 = v; i0 = e; }   // strict >: lowest index wins
      else if (v > v1) { v1 = v; i1 = e; }
    }
    const float e1 = expf(v1 - v0);
    const float inv = 1.f / (1.f + e1);
    topk_e[2 * n] = i0; topk_e[2 * n + 1] = i1;
    topk_s[2 * n] = inv; topk_s[2 * n + 1] = e1 * inv;
  }
}

// ------- Scatter: in-block histogram, padded offsets, permuted slot lists -------
__global__ __launch_bounds__(256) void scatter_k(
    int* __restrict__ meta, const int* __restrict__ topk_e,
    const float* __restrict__ topk_s, int* __restrict__ slot_token,
    float* __restrict__ slot_score) {
  __shared__ int cnt[4][8];
  __shared__ int soff[9];
  __shared__ int scur[8];
  const int t = threadIdx.x;
  const int wv = t >> 6;
  if (t < 32) cnt[t >> 3][t & 7] = 0;
  if (t < 8) scur[t] = 0;
  __syncthreads();
  for (int a = t; a < N_TOK * 2; a += 256)
    atomicAdd(&cnt[wv][topk_e[a]], 1);
  __syncthreads();
  if (t == 0) {
    int acc = 0;
    for (int e = 0; e < E_NUM; ++e) {
      const int c = cnt[0][e] + cnt[1][e] + cnt[2][e] + cnt[3][e];
      soff[e] = acc;
      meta[8 + e] = acc;
      acc += ((c + 127) / 128) * 128;
    }
    soff[8] = acc;
    meta[16] = acc;
  }
  __syncthreads();
  for (int a = t; a < N_TOK * 2; a += 256) {
    const int e = topk_e[a];
    const int pos = atomicAdd(&scur[e], 1);
    const int slot = soff[e] + pos;
    slot_token[slot] = a >> 1;
    slot_score[slot] = topk_s[a];
  }
}

// B lane->k map (k = lg*8 + h*4 + j, identical to A's fragment k map)
#define KLANE(l) (((l) >> 3 & 3) * 8 + ((l) >> 5) * 4 + (((l) & 7) >> 1))

// ============ GEMM1 (+w2 cvt tail): h = gelu(xb[gather] @ w1bf + b1) ============
// BM=128 BN=128 BK=32, 3-deep ring, 48KB LDS, 3 blocks/CU.
__global__ __launch_bounds__(256, 3) void gemm1_f(
    const unsigned short* __restrict__ xb, const unsigned short* __restrict__ wbf1,
    const float* __restrict__ b1, const int* __restrict__ meta,
    const int* __restrict__ slot_token, unsigned short* __restrict__ hbuf,
    const float* __restrict__ w2, unsigned short* __restrict__ wbf2) {
  __shared__ __align__(16) unsigned short Al[3 * 4096];  // [3][128 rows][32 k]
  __shared__ __align__(16) unsigned short Bl[3 * 4096];  // [3][8 regions][512]
  if (blockIdx.x >= G1_GRID) {   // fused tail: w2 f32 -> bf16 streaming
    cvt_stream(w2, wbf2, blockIdx.x - G1_GRID, CVT_BLKS, WCHUNKS);
    return;
  }
  const int total = meta[16];
  const int wgid = xcd_swz(blockIdx.x, G1_GRID);
  const int mt = wgid >> 5, nt = wgid & 31;
  const int m0 = mt * 128;
  if (m0 >= total) return;
  int exp = 0;
#pragma unroll
  for (int e = 1; e < E_NUM; ++e) if (m0 >= meta[8 + e]) exp = e;
  const int n0 = nt * 128;
  const int t = threadIdx.x, w = t >> 6, l = t & 63;
  const int wm = w >> 1, wn = w & 1, lr = l & 15, lg = l >> 4;

  // A staging: inst q = w*2+i covers rows q*16+(l>>2); chunk c = (l&3)^((l>>3)&3)
  const unsigned short* pA[2];
  const unsigned short* pB[2];
#pragma unroll
  for (int i = 0; i < 2; ++i) {
    const int q = w * 2 + i;
    const int row = q * 16 + (l >> 2);
    int tk = slot_token[m0 + row]; if (tk < 0) tk = 0;
    pA[i] = xb + (size_t)tk * H_DIM + (((l & 3) ^ ((l >> 3) & 3)) << 3);
    // B staging: region ri = q (cols ri*16..+16, k 0..31 subtiled for tr_read)
    pB[i] = wbf1 + (size_t)exp * H_DIM * F_DIM + (size_t)KLANE(l) * F_DIM
            + n0 + q * 16 + (l & 1) * 8;
  }

  const f32x4 fzero = {0.f, 0.f, 0.f, 0.f};
  f32x4 acc[4][4];
#pragma unroll
  for (int a = 0; a < 4; ++a)
#pragma unroll
    for (int b = 0; b < 4; ++b) acc[a][b] = fzero;

  const int fofs = ((lg ^ ((lr >> 1) & 3)) << 3);   // A read chunk (swizzled)

#define ISSUE1(Ad, Bd)                                                      \
  _Pragma("unroll") for (int i = 0; i < 2; ++i) {                           \
    gload_lds16(pA[i], (Ad) + (w * 2 + i) * 512); pA[i] += BK;              \
    gload_lds16(pB[i], (Bd) + (w * 2 + i) * 512); pB[i] += (size_t)BK * F_DIM; \
  }
#define MFMA1(Ac, Bc)                                                       \
  {                                                                         \
    lds_us bp = (lds_us)(Bc) + wn * 2048 + l * 4;                           \
    s16x8 af[4], bb[4];                                                     \
    _Pragma("unroll") for (int fm = 0; fm < 4; ++fm)                        \
      af[fm] = *(const s16x8*)&(Ac)[(wm * 64 + fm * 16 + lr) * 32 + fofs];  \
    ld_b4(bp, bb);                                                          \
    asm volatile("s_waitcnt lgkmcnt(0)" ::: "memory");                      \
    __builtin_amdgcn_sched_barrier(0);                                      \
    _Pragma("unroll") for (int fm = 0; fm < 4; ++fm)                        \
      _Pragma("unroll") for (int fn = 0; fn < 4; ++fn)                      \
        acc[fm][fn] = __builtin_amdgcn_mfma_f32_16x16x32_bf16(af[fm], bb[fn], acc[fm][fn], 0, 0, 0); \
  }

  const int NT = H_DIM / BK;  // 32
  ISSUE1(Al, Bl)              // tile 0 -> buf 0
  ISSUE1(Al + 4096, Bl + 4096)  // tile 1 -> buf 1
  int cur = 0;
  for (int kt = 0; kt < NT; ++kt) {
    if (kt + 1 < NT) asm volatile("s_waitcnt vmcnt(4)" ::: "memory");
    else             asm volatile("s_waitcnt vmcnt(0)" ::: "memory");
    __builtin_amdgcn_s_barrier();
    __builtin_amdgcn_sched_barrier(0);
    if (kt + 2 < NT) {
      int ib = cur + 2; if (ib >= 3) ib -= 3;
      ISSUE1(Al + ib * 4096, Bl + ib * 4096)
    }
    MFMA1(Al + cur * 4096, Bl + cur * 4096)
    ++cur; if (cur == 3) cur = 0;
  }

#pragma unroll
  for (int fn = 0; fn < 4; ++fn) {
    const int col = n0 + wn * 64 + fn * 16 + lr;
    const float bias = b1[exp * F_DIM + col];
#pragma unroll
    for (int fm = 0; fm < 4; ++fm) {
      const int rbase = m0 + wm * 64 + fm * 16 + lg * 4;
#pragma unroll
      for (int i = 0; i < 4; ++i) {
        hbuf[(size_t)(rbase + i) * F_DIM + col] = f2bf(fast_gelu(acc[fm][fn][i] + bias));
      }
    }
  }
}

// ============ GEMM2: out[token] += s*(hbuf @ w2bf + b2) ============
// BM=128 BN=64 BK=32, 3-deep ring, 36KB LDS, 4 blocks/CU.
__global__ __launch_bounds__(256, 4) void gemm2_f(
    const unsigned short* __restrict__ hbuf, const unsigned short* __restrict__ wbf2,
    const float* __restrict__ b2, const int* __restrict__ meta,
    const int* __restrict__ slot_token, const float* __restrict__ slot_score,
    float* __restrict__ out) {
  __shared__ __align__(16) unsigned short Al[3 * 4096];  // [3][128 rows][32 k]
  __shared__ __align__(16) unsigned short Bl[3 * 2048];  // [3][4 regions][512]
  const int total = meta[16];
  const int wgid = xcd_swz(blockIdx.x, G2_GRID);
  const int mt = wgid >> 4, nt = wgid & 15;
  const int m0 = mt * 128;
  if (m0 >= total) return;
  int exp = 0;
#pragma unroll
  for (int e = 1; e < E_NUM; ++e) if (m0 >= meta[8 + e]) exp = e;
  const int n0 = nt * 64;
  const int t = threadIdx.x, w = t >> 6, l = t & 63;
  const int wm = w >> 1, wn = w & 1, lr = l & 15, lg = l >> 4;

  const unsigned short* pA[2];
#pragma unroll
  for (int i = 0; i < 2; ++i) {
    const int q = w * 2 + i;
    const int row = q * 16 + (l >> 2);
    pA[i] = hbuf + (size_t)(m0 + row) * F_DIM + (((l & 3) ^ ((l >> 3) & 3)) << 3);
  }
  // B staging: region ri = w (cols w*16..+16)
  const unsigned short* pB = wbf2 + (size_t)exp * F_DIM * H_DIM
                             + (size_t)KLANE(l) * H_DIM + n0 + w * 16 + (l & 1) * 8;

  const f32x4 fzero = {0.f, 0.f, 0.f, 0.f};
  f32x4 acc[4][2];
#pragma unroll
  for (int a = 0; a < 4; ++a)
#pragma unroll
    for (int b = 0; b < 2; ++b) acc[a][b] = fzero;

  const int fofs = ((lg ^ ((lr >> 1) & 3)) << 3);

#define ISSUE2(Ad, Bd)                                                      \
  {                                                                         \
    _Pragma("unroll") for (int i = 0; i < 2; ++i) {                         \
      gload_lds16(pA[i], (Ad) + (w * 2 + i) * 512); pA[i] += BK;            \
    }                                                                       \
    gload_lds16(pB, (Bd) + w * 512); pB += (size_t)BK * H_DIM;              \
  }
#define MFMA2(Ac, Bc)                                                       \
  {                                                                         \
    lds_us bp = (lds_us)(Bc) + wn * 1024 + l * 4;                           \
    s16x8 af[4], bb[2];                                                     \
    _Pragma("unroll") for (int fm = 0; fm < 4; ++fm)                        \
      af[fm] = *(const s16x8*)&(Ac)[(wm * 64 + fm * 16 + lr) * 32 + fofs];  \
    ld_b2(bp, bb);                                                          \
    asm volatile("s_waitcnt lgkmcnt(0)" ::: "memory");                      \
    __builtin_amdgcn_sched_barrier(0);                                      \
    _Pragma("unroll") for (int fm = 0; fm < 4; ++fm)                        \
      _Pragma("unroll") for (int fn = 0; fn < 2; ++fn)                      \
        acc[fm][fn] = __builtin_amdgcn_mfma_f32_16x16x32_bf16(af[fm], bb[fn], acc[fm][fn], 0, 0, 0); \
  }

  const int NT = F_DIM / BK;  // 128
  ISSUE2(Al, Bl)
  ISSUE2(Al + 4096, Bl + 2048)
  int cur = 0;
  for (int kt = 0; kt < NT; ++kt) {
    if (kt + 1 < NT) asm volatile("s_waitcnt vmcnt(3)" ::: "memory");
    else             asm volatile("s_waitcnt vmcnt(0)" ::: "memory");
    __builtin_amdgcn_s_barrier();
    __builtin_amdgcn_sched_barrier(0);
    if (kt + 2 < NT) {
      int ib = cur + 2; if (ib >= 3) ib -= 3;
      ISSUE2(Al + ib * 4096, Bl + ib * 2048)
    }
    MFMA2(Al + cur * 4096, Bl + cur * 2048)
    ++cur; if (cur == 3) cur = 0;
  }

#pragma unroll
  for (int fm = 0; fm < 4; ++fm) {
    const int rbase = m0 + wm * 64 + fm * 16 + lg * 4;
    int toks[4]; float ss[4];
#pragma unroll
    for (int i = 0; i < 4; ++i) {
      toks[i] = slot_token[rbase + i];
      ss[i] = slot_score[rbase + i];
    }
#pragma unroll
    for (int fn = 0; fn < 2; ++fn) {
      const int col = n0 + wn * 32 + fn * 16 + lr;
      const float b2v = b2[exp * H_DIM + col];
#pragma unroll
      for (int i = 0; i < 4; ++i) {
        if (toks[i] >= 0)
          atomicAdd(out + (size_t)toks[i] * H_DIM + col, ss[i] * (acc[fm][fn][i] + b2v));
      }
    }
  }
}

// standalone w2 cvt for the low-ws sequential path
__global__ __launch_bounds__(256) void cvt2_k(const float* __restrict__ in,
                                              unsigned short* __restrict__ out) {
  cvt_stream(in, out, blockIdx.x, CVT_BLKS, WCHUNKS);
}

extern "C" void kernel_launch(void* const* d_in, const int* in_sizes, int n_in,
                              void* d_out, int out_size, void* d_ws, size_t ws_size,
                              hipStream_t stream) {
  const float* x  = (const float*)d_in[0];
  const float* rw = (const float*)d_in[1];
  const float* w1 = (const float*)d_in[2];
  const float* b1 = (const float*)d_in[3];
  const float* w2 = (const float*)d_in[4];
  const float* b2 = (const float*)d_in[5];
  float* out = (float*)d_out;
  char* ws = (char*)d_ws;

  int*   meta       = (int*)ws;
  int*   topk_e     = (int*)(ws + 4096);
  float* topk_s     = (float*)(ws + 20480);
  int*   slot_token = (int*)(ws + 36864);
  float* slot_score = (float*)(ws + 57344);
  unsigned short* xb   = (unsigned short*)(ws + (1ull << 20));
  unsigned short* hbuf = (unsigned short*)(ws + (8ull << 20));
  unsigned short* wbf1 = (unsigned short*)(ws + (48ull << 20));
  const size_t W = (size_t)E_NUM * H_DIM * F_DIM * 2;     // 64 MiB
  unsigned short* wbf2 = (unsigned short*)(ws + (48ull << 20) + W);
  const bool full = ws_size >= (48ull << 20) + 2 * W;     // 176 MiB
  if (!full) wbf2 = wbf1;   // sequential reuse

  hipMemsetAsync(meta, 0, 256, stream);
  hipMemsetAsync(slot_token, 0xFF, MAX_SLOTS * sizeof(int), stream);
  hipMemsetAsync(out, 0, (size_t)N_TOK * H_DIM * sizeof(float), stream);

  prep_k<<<CVT_BLKS + 128 + 512, 256, 0, stream>>>(w1, wbf1, x, xb, rw, topk_e, topk_s);
  scatter_k<<<1, 256, 0, stream>>>(meta, topk_e, topk_s, slot_token, slot_score);

  if (full) {
    gemm1_f<<<G1_GRID + CVT_BLKS, 256, 0, stream>>>(xb, wbf1, b1, meta, slot_token, hbuf, w2, wbf2);
  } else {
    gemm1_f<<<G1_GRID, 256, 0, stream>>>(xb, wbf1, b1, meta, slot_token, hbuf, w2, wbf2);
    cvt2_k<<<CVT_BLKS, 256, 0, stream>>>(w2, wbf2);
  }
  gemm2_f<<<G2_GRID, 256, 0, stream>>>(hbuf, wbf2, b2, meta, slot_token, slot_score, out);
}